// Round 11
// baseline (300.661 us; speedup 1.0000x reference)
//
#include <hip/hip_runtime.h>

#define EMBED 1024
#define SEQ 2048
#define BATCH 8

typedef __bf16 bf16;
typedef bf16 bf16x4 __attribute__((ext_vector_type(4)));
typedef bf16 bf16x8 __attribute__((ext_vector_type(8)));
typedef float f32x4 __attribute__((ext_vector_type(4)));

__device__ __forceinline__ void async_copy16(const bf16* g, bf16* l) {
  __builtin_amdgcn_global_load_lds(
      (const __attribute__((address_space(1))) unsigned int*)g,
      (__attribute__((address_space(3))) unsigned int*)l, 16, 0, 0);
}

// ============ 256x256 BK=64 GEMM core, m201-style 4-phase ============
// C = A * B^T, bf16, 512 thr = 8 waves (2M x 4N), per-wave 128x64 out.
// LDS: 2 buffers x (A 32KB + B 32KB) = 128 KiB.
// Per phase: {ds-read frags | stage 1-2 units of tile t+1 | barrier |
//   lgkmcnt(0) | 16 MFMA | counted-vmcnt gate | barrier}.
// EXTRA (E VMEM ops): an optional per-tile VMEM unit (fused BW work) issued
// after p3's MFMA, BEFORE the p3 gate. FIFO ledger with extras:
//   p3 gate: newer-than-{B',A01'} = A23'(2)+extra(E) -> vmcnt(2+E)
//   p1 gate (t>=1): newer-than-A23 = extra(E)+B0''(2)+B1''(2) -> vmcnt(4+E)
//   p1 gate (t==0): no extra in FIFO yet -> vmcnt(4)
template <int KDEPTH, int LDA, int LDB, int E, class ExtraF>
__device__ __forceinline__ void gemm_core(const bf16* __restrict__ Ab,
                                          const bf16* __restrict__ Bb,
                                          bf16* lds, f32x4 (&acc)[8][4],
                                          ExtraF&& extra) {
  const int tid = (int)threadIdx.x;
  const int lane = tid & 63;
  const int wid = tid >> 6;
  const int wm = wid >> 2, wn = wid & 3;
  const int c = lane & 15, g = lane >> 4;
  const int sx = c & 7;
  constexpr int NT = KDEPTH / 64;

  // B-half stage: half h = rows h*128..h*128+128, 2 instrs/thread (16 KB)
  auto stage_B = [&](int h, int t) {
    bf16* dst = lds + (t & 1) * 32768 + 16384 + h * 8192;
    const int k0 = t * 64;
    const bf16* src = Bb + (size_t)(h * 128) * LDB + k0;
#pragma unroll
    for (int r = 0; r < 2; ++r) {
      int idx = r * 512 + tid;  // chunk within half: row=idx>>3, slot=idx&7
      int row = idx >> 3, slot = idx & 7;
      async_copy16(src + (size_t)row * LDB + ((slot ^ (row & 7)) * 8), dst + idx * 8);
    }
  };
  // A-quarter stage: block q = 64 rows (both wm halves), 1 instr/thread (8 KB)
  auto stage_A = [&](int q, int t) {
    bf16* dst = lds + (t & 1) * 32768 + q * 4096;
    const int k0 = t * 64;
    int rib = tid >> 3, slot = tid & 7;  // rib 0..63: 0-31 -> wm0, 32-63 -> wm1
    int grow = q * 32 + (rib & 31) + (rib >> 5) * 128;
    async_copy16(Ab + (size_t)grow * LDA + k0 + ((slot ^ (rib & 7)) * 8), dst + tid * 8);
  };

  // prologue: full tile 0 (FIFO: B0,B1,q0,q1,q2,q3); q2,q3 may still fly
  stage_B(0, 0); stage_B(1, 0);
  stage_A(0, 0); stage_A(1, 0); stage_A(2, 0); stage_A(3, 0);
  asm volatile("s_waitcnt vmcnt(2)" ::: "memory");  // B + q0,q1 landed (mine)
  __builtin_amdgcn_s_barrier();                     // (everyone)
  __builtin_amdgcn_sched_barrier(0);

  const int boffb = (wn * 64 + c) * 64;
  const int arowb = (wm * 32 + c) * 64;

  for (int t = 0; t < NT; ++t) {
    const bf16* bufA = lds + (t & 1) * 32768;
    const bf16* bufB = bufA + 16384;
    const int nxt = t + 1;
    const bool more = nxt < NT;
    bf16x8 bfr[4][2];
#pragma unroll
    for (int p = 0; p < 4; ++p) {
      // ---- ds-reads for THIS phase ----
      bf16x8 afr[2][2];
#pragma unroll
      for (int mm = 0; mm < 2; ++mm)
#pragma unroll
        for (int ks = 0; ks < 2; ++ks)
          afr[mm][ks] = *reinterpret_cast<const bf16x8*>(
              bufA + p * 4096 + arowb + mm * 1024 + (((ks * 4 + g) ^ sx) * 8));
      if (p == 0) {
#pragma unroll
        for (int ni = 0; ni < 4; ++ni)
#pragma unroll
          for (int ks = 0; ks < 2; ++ks)
            bfr[ni][ks] = *reinterpret_cast<const bf16x8*>(
                bufB + boffb + ni * 1024 + (((ks * 4 + g) ^ sx) * 8));
      }
      // ---- stage prefetch units for tile t+1 ----
      if (more) {
        if (p == 0) stage_B(0, nxt);
        else if (p == 1) stage_B(1, nxt);
        else if (p == 2) { stage_A(0, nxt); stage_A(1, nxt); }
        else { stage_A(2, nxt); stage_A(3, nxt); }
      }
      __builtin_amdgcn_s_barrier();
      asm volatile("s_waitcnt lgkmcnt(0)" ::: "memory");
      __builtin_amdgcn_sched_barrier(0);
      __builtin_amdgcn_s_setprio(1);
#pragma unroll
      for (int mm = 0; mm < 2; ++mm)
#pragma unroll
        for (int ni = 0; ni < 4; ++ni)
#pragma unroll
          for (int ks = 0; ks < 2; ++ks)
            acc[p * 2 + mm][ni] = __builtin_amdgcn_mfma_f32_16x16x32_bf16(
                afr[mm][ks], bfr[ni][ks], acc[p * 2 + mm][ni], 0, 0, 0);
      __builtin_amdgcn_s_setprio(0);
      __builtin_amdgcn_sched_barrier(0);
      if (p == 1) {
        if (more) {
          if constexpr (E > 0) {
            if (t == 0)
              asm volatile("s_waitcnt vmcnt(4)" ::: "memory");
            else
              asm volatile("s_waitcnt vmcnt(%0)" ::"i"(4 + E) : "memory");
          } else {
            asm volatile("s_waitcnt vmcnt(4)" ::: "memory");
          }
        } else {
          asm volatile("s_waitcnt vmcnt(0)" ::: "memory");
        }
      }
      if (p == 3) {
        extra(t);  // E VMEM ops enter the FIFO here (newest)
        __builtin_amdgcn_sched_barrier(0);
        if (more)
          asm volatile("s_waitcnt vmcnt(%0)" ::"i"(2 + E) : "memory");
        else
          asm volatile("s_waitcnt vmcnt(0)" ::: "memory");
      }
      __builtin_amdgcn_s_barrier();
    }
  }
}

struct NoExtra {
  __device__ void operator()(int) const {}
};

// ------------- fused W-convert + LayerNorm (block-granular split) ---------
__global__ __launch_bounds__(256) void k_pre(const float* __restrict__ x,
                                             const float* __restrict__ gamma,
                                             const float* __restrict__ beta,
                                             const float* __restrict__ wq,
                                             const float* __restrict__ wk,
                                             const float* __restrict__ wv,
                                             bf16* __restrict__ xn,
                                             bf16* __restrict__ wall) {
  const int bid = (int)blockIdx.x;
  const int tid = (int)threadIdx.x;
  if (bid >= BATCH * SEQ) {
    int i4 = (bid - BATCH * SEQ) * 256 + tid;
    int m = i4 >> 18;
    int loc = i4 & 262143;
    const float* src = (m == 0) ? wq : (m == 1) ? wk : wv;
    float4 v = reinterpret_cast<const float4*>(src)[loc];
    bf16x4 o;
    o[0] = (bf16)v.x; o[1] = (bf16)v.y; o[2] = (bf16)v.z; o[3] = (bf16)v.w;
    reinterpret_cast<bf16x4*>(wall)[i4] = o;
    return;
  }
  const int row = bid;
  const float4 v = reinterpret_cast<const float4*>(x + (size_t)row * EMBED)[tid];
  float s = v.x + v.y + v.z + v.w;
  float q = v.x * v.x + v.y * v.y + v.z * v.z + v.w * v.w;
#pragma unroll
  for (int off = 1; off < 64; off <<= 1) {
    s += __shfl_xor(s, off);
    q += __shfl_xor(q, off);
  }
  __shared__ float ls[4], lq[4];
  int w = tid >> 6;
  if ((tid & 63) == 0) { ls[w] = s; lq[w] = q; }
  __syncthreads();
  s = ls[0] + ls[1] + ls[2] + ls[3];
  q = lq[0] + lq[1] + lq[2] + lq[3];
  float mean = s * (1.0f / EMBED);
  float var = q * (1.0f / EMBED) - mean * mean;
  float rstd = rsqrtf(var + 1e-5f);
  float4 gm = reinterpret_cast<const float4*>(gamma)[tid];
  float4 b = reinterpret_cast<const float4*>(beta)[tid];
  bf16x4 o;
  o[0] = (bf16)((v.x - mean) * rstd * gm.x + b.x);
  o[1] = (bf16)((v.y - mean) * rstd * gm.y + b.y);
  o[2] = (bf16)((v.z - mean) * rstd * gm.z + b.z);
  o[3] = (bf16)((v.w - mean) * rstd * gm.w + b.w);
  reinterpret_cast<bf16x4*>(xn + (size_t)row * EMBED)[tid] = o;
}

// ---------------- QKV projection, XCD-chunked 1D grid (768) ----------------
__global__ __launch_bounds__(512) void k_qkv256(const bf16* __restrict__ xn,
                                                const bf16* __restrict__ wall,
                                                const float* __restrict__ bq,
                                                const float* __restrict__ bk,
                                                const float* __restrict__ bv,
                                                bf16* __restrict__ qbuf,
                                                bf16* __restrict__ kbuf,
                                                bf16* __restrict__ vt) {
  extern __shared__ bf16 smem[];
  const int h = (int)blockIdx.x;
  const int xcd = h & 7, pos = h >> 3;
  const int z = pos >> 5;
  const int mtile = xcd * 8 + ((pos >> 2) & 7);
  const int ntile = pos & 3;
  const int tid = (int)threadIdx.x, lane = tid & 63, wid = tid >> 6;
  const int wm = wid >> 2, wn = wid & 3;
  const int cc = lane & 15, g = lane >> 4;
  const bf16* Ab = xn + (size_t)(mtile * 256) * EMBED;
  const bf16* Bb = wall + (size_t)z * EMBED * EMBED + (size_t)(ntile * 256) * EMBED;
  f32x4 acc[8][4];
#pragma unroll
  for (int i = 0; i < 8; ++i)
#pragma unroll
    for (int j = 0; j < 4; ++j) acc[i][j] = (f32x4){0.f, 0.f, 0.f, 0.f};
  gemm_core<EMBED, EMBED, EMBED, 0>(Ab, Bb, smem, acc, NoExtra{});

  const int c0 = ntile * 256 + wn * 64;
  const int r0 = mtile * 256 + wm * 128;
  if (z < 2) {
    bf16* o = z ? kbuf : qbuf;
    const float* bias = z ? bk : bq;
#pragma unroll
    for (int mi = 0; mi < 8; ++mi)
#pragma unroll
      for (int ni = 0; ni < 4; ++ni) {
        int col = c0 + ni * 16 + cc;
        float bb = bias[col];
#pragma unroll
        for (int j = 0; j < 4; ++j)
          o[(size_t)(r0 + mi * 16 + g * 4 + j) * EMBED + col] = (bf16)(acc[mi][ni][j] + bb);
      }
  } else {
#pragma unroll
    for (int mi = 0; mi < 8; ++mi) {
      int srow = r0 + mi * 16 + g * 4;
      int b = srow >> 11, sl = srow & (SEQ - 1);
#pragma unroll
      for (int ni = 0; ni < 4; ++ni) {
        int col = c0 + ni * 16 + cc;
        float bb = bv[col];
        bf16x4 pk;
#pragma unroll
        for (int j = 0; j < 4; ++j) pk[j] = (bf16)(acc[mi][ni][j] + bb);
        *reinterpret_cast<bf16x4*>(vt + (size_t)b * EMBED * SEQ + (size_t)col * SEQ + sl) = pk;
      }
    }
  }
}

// ------- Scores: XCD-chunked 1D grid (512); XCD k <- batch k ----------
__global__ __launch_bounds__(512) void k_scores256(const bf16* __restrict__ qm,
                                                   const bf16* __restrict__ km,
                                                   bf16* __restrict__ wbf,
                                                   float* __restrict__ partial) {
  extern __shared__ bf16 smem[];
  const int h = (int)blockIdx.x;
  const int bb = h & 7, pos = h >> 3;
  const int mtile = pos >> 3, ntile = pos & 7;
  const int tid = (int)threadIdx.x, lane = tid & 63, wid = tid >> 6;
  const int wm = wid >> 2, wn = wid & 3;
  const int cc = lane & 15, g = lane >> 4;
  const bf16* Ab = qm + (size_t)bb * SEQ * EMBED + (size_t)(mtile * 256) * EMBED;
  const bf16* Bb = km + (size_t)bb * SEQ * EMBED + (size_t)(ntile * 256) * EMBED;
  f32x4 acc[8][4];
#pragma unroll
  for (int i = 0; i < 8; ++i)
#pragma unroll
    for (int j = 0; j < 4; ++j) acc[i][j] = (f32x4){0.f, 0.f, 0.f, 0.f};
  gemm_core<EMBED, EMBED, EMBED, 0>(Ab, Bb, smem, acc, NoExtra{});

  float* red = (float*)smem;  // 256 rows x 4 waveN
  const int c0 = ntile * 256 + wn * 64;
#pragma unroll
  for (int mi = 0; mi < 8; ++mi) {
#pragma unroll
    for (int j = 0; j < 4; ++j) {
      int lrow = wm * 128 + mi * 16 + g * 4 + j;
      size_t grow = (size_t)bb * SEQ + mtile * 256 + lrow;
      float s = 0.f;
#pragma unroll
      for (int ni = 0; ni < 4; ++ni) {
        float e = __expf(acc[mi][ni][j] * 0.03125f);
        wbf[grow * SEQ + c0 + ni * 16 + cc] = (bf16)e;
        s += e;
      }
      s += __shfl_xor(s, 1);
      s += __shfl_xor(s, 2);
      s += __shfl_xor(s, 4);
      s += __shfl_xor(s, 8);
      if (cc == 0) red[lrow * 4 + wn] = s;
    }
  }
  __syncthreads();
  if (tid < 256) {
    float l = red[tid * 4 + 0] + red[tid * 4 + 1] + red[tid * 4 + 2] + red[tid * 4 + 3];
    partial[((size_t)bb * SEQ + mtile * 256 + tid) * 8 + ntile] = l;
  }
}

// ---------------- rowsum -> rinv ----------------
__global__ __launch_bounds__(256) void k_rowsum(const float* __restrict__ partial,
                                                float* __restrict__ rinv) {
  int row = blockIdx.x * 256 + threadIdx.x;
  const float* p = partial + (size_t)row * 8;
  float l = 0.f;
#pragma unroll
  for (int i = 0; i < 8; ++i) l += p[i];
  rinv[row] = 1.0f / l;
}

// ------- PV + fused normalize: XCD-chunked 1D grid (256) -------------------
// GEMM: out = x + (wbf . vt^T) * rinv.  Fused per-tile extra unit (E=4 VMEM
// ops): one 8-elem chunk of attn_fp32 = bf16(exp) * rinv per thread per tile.
// 256 blocks x 32 tiles x 512 thr = 4194304 chunks = full attn matrix.
__global__ __launch_bounds__(512) void k_pv256(const bf16* __restrict__ wbf,
                                               const bf16* __restrict__ vt,
                                               const float* __restrict__ rinv,
                                               const float* __restrict__ xin,
                                               float* __restrict__ outp,
                                               float* __restrict__ attn) {
  extern __shared__ bf16 smem[];
  const int h = (int)blockIdx.x;
  const int bb = h & 7, pos = h >> 3;
  const int mtile = pos >> 2, ntile = pos & 3;
  const int tid = (int)threadIdx.x, lane = tid & 63, wid = tid >> 6;
  const int wm = wid >> 2, wn = wid & 3;
  const int cc = lane & 15, g = lane >> 4;
  const bf16* Ab = wbf + (size_t)bb * SEQ * SEQ + (size_t)(mtile * 256) * SEQ;
  const bf16* Bb = vt + (size_t)bb * EMBED * SEQ + (size_t)(ntile * 256) * SEQ;
  const size_t nbase = (size_t)h * 16384 + tid;
  f32x4 acc[8][4];
#pragma unroll
  for (int i = 0; i < 8; ++i)
#pragma unroll
    for (int j = 0; j < 4; ++j) acc[i][j] = (f32x4){0.f, 0.f, 0.f, 0.f};

  auto norm_unit = [&](int t) {
    size_t c = nbase + (size_t)t * 512;
    int row = (int)(c >> 8);  // 256 chunks per 2048-elem row
    float ri = rinv[row];
    bf16x8 v = reinterpret_cast<const bf16x8*>(wbf)[c];
    float4 lo, hi;
    lo.x = (float)v[0] * ri; lo.y = (float)v[1] * ri;
    lo.z = (float)v[2] * ri; lo.w = (float)v[3] * ri;
    hi.x = (float)v[4] * ri; hi.y = (float)v[5] * ri;
    hi.z = (float)v[6] * ri; hi.w = (float)v[7] * ri;
    reinterpret_cast<float4*>(attn)[c * 2] = lo;
    reinterpret_cast<float4*>(attn)[c * 2 + 1] = hi;
  };

  gemm_core<SEQ, SEQ, SEQ, 4>(Ab, Bb, smem, acc, norm_unit);

  const int c0 = ntile * 256 + wn * 64;
#pragma unroll
  for (int mi = 0; mi < 8; ++mi) {
#pragma unroll
    for (int j = 0; j < 4; ++j) {
      size_t grow = (size_t)bb * SEQ + mtile * 256 + wm * 128 + mi * 16 + g * 4 + j;
      float ri = rinv[grow];
      size_t base = grow * EMBED;
#pragma unroll
      for (int ni = 0; ni < 4; ++ni) {
        size_t off = base + c0 + ni * 16 + cc;
        outp[off] = xin[off] + acc[mi][ni][j] * ri;
      }
    }
  }
}

extern "C" void kernel_launch(void* const* d_in, const int* in_sizes, int n_in,
                              void* d_out, int out_size, void* d_ws, size_t ws_size,
                              hipStream_t stream) {
  const float* x = (const float*)d_in[0];
  const float* Wq = (const float*)d_in[1];
  const float* bq = (const float*)d_in[2];
  const float* Wk = (const float*)d_in[3];
  const float* bk = (const float*)d_in[4];
  const float* Wv = (const float*)d_in[5];
  const float* bv = (const float*)d_in[6];
  const float* gamma = (const float*)d_in[7];
  const float* beta = (const float*)d_in[8];

  float* out = (float*)d_out;
  float* attn = out + (size_t)BATCH * SEQ * EMBED;

  bf16* qbuf = (bf16*)d_out;  // Q,K live in the output region until PV
  bf16* kbuf = qbuf + (size_t)BATCH * SEQ * EMBED;

  // ws: [0,32M) xn | [32M,38M) W bf16 | later [0,64M) wbf | [64M,96M) Vt
  //     [96M,96.5M) partial (16384x8 f32) | [96.5M,+64K) rinv
  bf16* xn = (bf16*)d_ws;
  bf16* wall = xn + (size_t)BATCH * SEQ * EMBED;
  bf16* wbf = (bf16*)d_ws;
  bf16* vt = (bf16*)d_ws + (size_t)BATCH * SEQ * SEQ;
  float* partial = (float*)((char*)d_ws + 100663296ull);
  float* rinv = (float*)((char*)d_ws + 100663296ull + 524288ull);

  hipFuncSetAttribute((const void*)k_qkv256, hipFuncAttributeMaxDynamicSharedMemorySize, 131072);
  hipFuncSetAttribute((const void*)k_scores256, hipFuncAttributeMaxDynamicSharedMemorySize, 131072);
  hipFuncSetAttribute((const void*)k_pv256, hipFuncAttributeMaxDynamicSharedMemorySize, 131072);

  k_pre<<<BATCH * SEQ + 3072, 256, 0, stream>>>(x, gamma, beta, Wq, Wk, Wv, xn, wall);
  k_qkv256<<<768, 512, 131072, stream>>>(xn, wall, bq, bk, bv, qbuf, kbuf, vt);
  k_scores256<<<512, 512, 131072, stream>>>(qbuf, kbuf, wbf, partial);
  k_rowsum<<<64, 256, 0, stream>>>(partial, rinv);
  k_pv256<<<256, 512, 131072, stream>>>(wbf, vt, rinv, x, out, attn);
}

// Round 12
// 297.472 us; speedup vs baseline: 1.0107x; 1.0107x over previous
//
#include <hip/hip_runtime.h>

#define EMBED 1024
#define SEQ 2048
#define BATCH 8

typedef __bf16 bf16;
typedef bf16 bf16x4 __attribute__((ext_vector_type(4)));
typedef bf16 bf16x8 __attribute__((ext_vector_type(8)));
typedef float f32x4 __attribute__((ext_vector_type(4)));

__device__ __forceinline__ void async_copy16(const bf16* g, bf16* l) {
  __builtin_amdgcn_global_load_lds(
      (const __attribute__((address_space(1))) unsigned int*)g,
      (__attribute__((address_space(3))) unsigned int*)l, 16, 0, 0);
}

// ============ 256x256 BK=64 GEMM core, m201-style 4-phase ============
// (round-10 proven version, verbatim)
// C = A * B^T, bf16, 512 thr = 8 waves (2M x 4N), per-wave 128x64 out.
// LDS: 2 buffers x (A 32KB + B 32KB) = 128 KiB.
// A stored as 4 quarter-blocks: block q = rows {q*32..+32} U {128+q*32..+32}.
// Per phase: {ds-read frags | stage 1-2 units of tile t+1 | barrier |
//   lgkmcnt(0) | 16 MFMA | counted-vmcnt gate | barrier}.
// FIFO gates: end-p1 vmcnt(4) => A-q2,q3(t) landed; end-p3 vmcnt(2) =>
//   B(t+1)+A-q0,q1(t+1) landed. Never drains to 0 mid-loop.
template <int KDEPTH, int LDA, int LDB>
__device__ __forceinline__ void gemm_core(const bf16* __restrict__ Ab,
                                          const bf16* __restrict__ Bb,
                                          bf16* lds, f32x4 (&acc)[8][4]) {
  const int tid = (int)threadIdx.x;
  const int lane = tid & 63;
  const int wid = tid >> 6;
  const int wm = wid >> 2, wn = wid & 3;
  const int c = lane & 15, g = lane >> 4;
  const int sx = c & 7;
  constexpr int NT = KDEPTH / 64;

  auto stage_B = [&](int h, int t) {
    bf16* dst = lds + (t & 1) * 32768 + 16384 + h * 8192;
    const int k0 = t * 64;
    const bf16* src = Bb + (size_t)(h * 128) * LDB + k0;
#pragma unroll
    for (int r = 0; r < 2; ++r) {
      int idx = r * 512 + tid;
      int row = idx >> 3, slot = idx & 7;
      async_copy16(src + (size_t)row * LDB + ((slot ^ (row & 7)) * 8), dst + idx * 8);
    }
  };
  auto stage_A = [&](int q, int t) {
    bf16* dst = lds + (t & 1) * 32768 + q * 4096;
    const int k0 = t * 64;
    int rib = tid >> 3, slot = tid & 7;
    int grow = q * 32 + (rib & 31) + (rib >> 5) * 128;
    async_copy16(Ab + (size_t)grow * LDA + k0 + ((slot ^ (rib & 7)) * 8), dst + tid * 8);
  };

  stage_B(0, 0); stage_B(1, 0);
  stage_A(0, 0); stage_A(1, 0); stage_A(2, 0); stage_A(3, 0);
  asm volatile("s_waitcnt vmcnt(2)" ::: "memory");
  __builtin_amdgcn_s_barrier();
  __builtin_amdgcn_sched_barrier(0);

  const int boffb = (wn * 64 + c) * 64;
  const int arowb = (wm * 32 + c) * 64;

  for (int t = 0; t < NT; ++t) {
    const bf16* bufA = lds + (t & 1) * 32768;
    const bf16* bufB = bufA + 16384;
    const int nxt = t + 1;
    const bool more = nxt < NT;
    bf16x8 bfr[4][2];
#pragma unroll
    for (int p = 0; p < 4; ++p) {
      bf16x8 afr[2][2];
#pragma unroll
      for (int mm = 0; mm < 2; ++mm)
#pragma unroll
        for (int ks = 0; ks < 2; ++ks)
          afr[mm][ks] = *reinterpret_cast<const bf16x8*>(
              bufA + p * 4096 + arowb + mm * 1024 + (((ks * 4 + g) ^ sx) * 8));
      if (p == 0) {
#pragma unroll
        for (int ni = 0; ni < 4; ++ni)
#pragma unroll
          for (int ks = 0; ks < 2; ++ks)
            bfr[ni][ks] = *reinterpret_cast<const bf16x8*>(
                bufB + boffb + ni * 1024 + (((ks * 4 + g) ^ sx) * 8));
      }
      if (more) {
        if (p == 0) stage_B(0, nxt);
        else if (p == 1) stage_B(1, nxt);
        else if (p == 2) { stage_A(0, nxt); stage_A(1, nxt); }
        else { stage_A(2, nxt); stage_A(3, nxt); }
      }
      __builtin_amdgcn_s_barrier();
      asm volatile("s_waitcnt lgkmcnt(0)" ::: "memory");
      __builtin_amdgcn_sched_barrier(0);
      __builtin_amdgcn_s_setprio(1);
#pragma unroll
      for (int mm = 0; mm < 2; ++mm)
#pragma unroll
        for (int ni = 0; ni < 4; ++ni)
#pragma unroll
          for (int ks = 0; ks < 2; ++ks)
            acc[p * 2 + mm][ni] = __builtin_amdgcn_mfma_f32_16x16x32_bf16(
                afr[mm][ks], bfr[ni][ks], acc[p * 2 + mm][ni], 0, 0, 0);
      __builtin_amdgcn_s_setprio(0);
      __builtin_amdgcn_sched_barrier(0);
      if (p == 1) {
        if (more) asm volatile("s_waitcnt vmcnt(4)" ::: "memory");
        else      asm volatile("s_waitcnt vmcnt(0)" ::: "memory");
      }
      if (p == 3) {
        if (more) asm volatile("s_waitcnt vmcnt(2)" ::: "memory");
        else      asm volatile("s_waitcnt vmcnt(0)" ::: "memory");
      }
      __builtin_amdgcn_s_barrier();
    }
  }
}

// ------------- fused W-convert + LayerNorm (block-granular split) ---------
__global__ __launch_bounds__(256) void k_pre(const float* __restrict__ x,
                                             const float* __restrict__ gamma,
                                             const float* __restrict__ beta,
                                             const float* __restrict__ wq,
                                             const float* __restrict__ wk,
                                             const float* __restrict__ wv,
                                             bf16* __restrict__ xn,
                                             bf16* __restrict__ wall) {
  const int bid = (int)blockIdx.x;
  const int tid = (int)threadIdx.x;
  if (bid >= BATCH * SEQ) {
    int i4 = (bid - BATCH * SEQ) * 256 + tid;
    int m = i4 >> 18;
    int loc = i4 & 262143;
    const float* src = (m == 0) ? wq : (m == 1) ? wk : wv;
    float4 v = reinterpret_cast<const float4*>(src)[loc];
    bf16x4 o;
    o[0] = (bf16)v.x; o[1] = (bf16)v.y; o[2] = (bf16)v.z; o[3] = (bf16)v.w;
    reinterpret_cast<bf16x4*>(wall)[i4] = o;
    return;
  }
  const int row = bid;
  const float4 v = reinterpret_cast<const float4*>(x + (size_t)row * EMBED)[tid];
  float s = v.x + v.y + v.z + v.w;
  float q = v.x * v.x + v.y * v.y + v.z * v.z + v.w * v.w;
#pragma unroll
  for (int off = 1; off < 64; off <<= 1) {
    s += __shfl_xor(s, off);
    q += __shfl_xor(q, off);
  }
  __shared__ float ls[4], lq[4];
  int w = tid >> 6;
  if ((tid & 63) == 0) { ls[w] = s; lq[w] = q; }
  __syncthreads();
  s = ls[0] + ls[1] + ls[2] + ls[3];
  q = lq[0] + lq[1] + lq[2] + lq[3];
  float mean = s * (1.0f / EMBED);
  float var = q * (1.0f / EMBED) - mean * mean;
  float rstd = rsqrtf(var + 1e-5f);
  float4 gm = reinterpret_cast<const float4*>(gamma)[tid];
  float4 b = reinterpret_cast<const float4*>(beta)[tid];
  bf16x4 o;
  o[0] = (bf16)((v.x - mean) * rstd * gm.x + b.x);
  o[1] = (bf16)((v.y - mean) * rstd * gm.y + b.y);
  o[2] = (bf16)((v.z - mean) * rstd * gm.z + b.z);
  o[3] = (bf16)((v.w - mean) * rstd * gm.w + b.w);
  reinterpret_cast<bf16x4*>(xn + (size_t)row * EMBED)[tid] = o;
}

// ---------------- QKV projection, XCD-chunked 1D grid (768) ----------------
__global__ __launch_bounds__(512) void k_qkv256(const bf16* __restrict__ xn,
                                                const bf16* __restrict__ wall,
                                                const float* __restrict__ bq,
                                                const float* __restrict__ bk,
                                                const float* __restrict__ bv,
                                                bf16* __restrict__ qbuf,
                                                bf16* __restrict__ kbuf,
                                                bf16* __restrict__ vt) {
  extern __shared__ bf16 smem[];
  const int h = (int)blockIdx.x;
  const int xcd = h & 7, pos = h >> 3;
  const int z = pos >> 5;
  const int mtile = xcd * 8 + ((pos >> 2) & 7);
  const int ntile = pos & 3;
  const int tid = (int)threadIdx.x, lane = tid & 63, wid = tid >> 6;
  const int wm = wid >> 2, wn = wid & 3;
  const int cc = lane & 15, g = lane >> 4;
  const bf16* Ab = xn + (size_t)(mtile * 256) * EMBED;
  const bf16* Bb = wall + (size_t)z * EMBED * EMBED + (size_t)(ntile * 256) * EMBED;
  f32x4 acc[8][4];
#pragma unroll
  for (int i = 0; i < 8; ++i)
#pragma unroll
    for (int j = 0; j < 4; ++j) acc[i][j] = (f32x4){0.f, 0.f, 0.f, 0.f};
  gemm_core<EMBED, EMBED, EMBED>(Ab, Bb, smem, acc);

  const int c0 = ntile * 256 + wn * 64;
  const int r0 = mtile * 256 + wm * 128;
  if (z < 2) {
    bf16* o = z ? kbuf : qbuf;
    const float* bias = z ? bk : bq;
#pragma unroll
    for (int mi = 0; mi < 8; ++mi)
#pragma unroll
      for (int ni = 0; ni < 4; ++ni) {
        int col = c0 + ni * 16 + cc;
        float bb = bias[col];
#pragma unroll
        for (int j = 0; j < 4; ++j)
          o[(size_t)(r0 + mi * 16 + g * 4 + j) * EMBED + col] = (bf16)(acc[mi][ni][j] + bb);
      }
  } else {
#pragma unroll
    for (int mi = 0; mi < 8; ++mi) {
      int srow = r0 + mi * 16 + g * 4;
      int b = srow >> 11, sl = srow & (SEQ - 1);
#pragma unroll
      for (int ni = 0; ni < 4; ++ni) {
        int col = c0 + ni * 16 + cc;
        float bb = bv[col];
        bf16x4 pk;
#pragma unroll
        for (int j = 0; j < 4; ++j) pk[j] = (bf16)(acc[mi][ni][j] + bb);
        *reinterpret_cast<bf16x4*>(vt + (size_t)b * EMBED * SEQ + (size_t)col * SEQ + sl) = pk;
      }
    }
  }
}

// ------- Scores: XCD-chunked 1D grid (512); XCD k <- batch k ----------
__global__ __launch_bounds__(512) void k_scores256(const bf16* __restrict__ qm,
                                                   const bf16* __restrict__ km,
                                                   bf16* __restrict__ wbf,
                                                   float* __restrict__ partial) {
  extern __shared__ bf16 smem[];
  const int h = (int)blockIdx.x;
  const int bb = h & 7, pos = h >> 3;
  const int mtile = pos >> 3, ntile = pos & 7;
  const int tid = (int)threadIdx.x, lane = tid & 63, wid = tid >> 6;
  const int wm = wid >> 2, wn = wid & 3;
  const int cc = lane & 15, g = lane >> 4;
  const bf16* Ab = qm + (size_t)bb * SEQ * EMBED + (size_t)(mtile * 256) * EMBED;
  const bf16* Bb = km + (size_t)bb * SEQ * EMBED + (size_t)(ntile * 256) * EMBED;
  f32x4 acc[8][4];
#pragma unroll
  for (int i = 0; i < 8; ++i)
#pragma unroll
    for (int j = 0; j < 4; ++j) acc[i][j] = (f32x4){0.f, 0.f, 0.f, 0.f};
  gemm_core<EMBED, EMBED, EMBED>(Ab, Bb, smem, acc);

  float* red = (float*)smem;  // 256 rows x 4 waveN
  const int c0 = ntile * 256 + wn * 64;
#pragma unroll
  for (int mi = 0; mi < 8; ++mi) {
#pragma unroll
    for (int j = 0; j < 4; ++j) {
      int lrow = wm * 128 + mi * 16 + g * 4 + j;
      size_t grow = (size_t)bb * SEQ + mtile * 256 + lrow;
      float s = 0.f;
#pragma unroll
      for (int ni = 0; ni < 4; ++ni) {
        float e = __expf(acc[mi][ni][j] * 0.03125f);
        wbf[grow * SEQ + c0 + ni * 16 + cc] = (bf16)e;
        s += e;
      }
      s += __shfl_xor(s, 1);
      s += __shfl_xor(s, 2);
      s += __shfl_xor(s, 4);
      s += __shfl_xor(s, 8);
      if (cc == 0) red[lrow * 4 + wn] = s;
    }
  }
  __syncthreads();
  if (tid < 256) {
    float l = red[tid * 4 + 0] + red[tid * 4 + 1] + red[tid * 4 + 2] + red[tid * 4 + 3];
    partial[((size_t)bb * SEQ + mtile * 256 + tid) * 8 + ntile] = l;
  }
}

// ---------------- rowsum -> rinv ----------------
__global__ __launch_bounds__(256) void k_rowsum(const float* __restrict__ partial,
                                                float* __restrict__ rinv) {
  int row = blockIdx.x * 256 + threadIdx.x;
  const float* p = partial + (size_t)row * 8;
  float l = 0.f;
#pragma unroll
  for (int i = 0; i < 8; ++i) l += p[i];
  rinv[row] = 1.0f / l;
}

// ------- PV (round-10 core) + norm-backfill blocks -------------------------
// Blocks h<256: pv GEMM, XCD-chunked (XCD k <- batch k), out = x + PV*rinv.
// Blocks h>=256 (1024 blocks): stream attn_fp32 = bf16(exp)*rinv; they
// backfill CUs as pv blocks finish, overlapping the 192 MB norm pass with
// pv's tail instead of serializing after it. 1024 x 512thr x 8 = 4194304
// chunks = full attn matrix.
__global__ __launch_bounds__(512) void k_pv256(const bf16* __restrict__ wbf,
                                               const bf16* __restrict__ vt,
                                               const float* __restrict__ rinv,
                                               const float* __restrict__ xin,
                                               float* __restrict__ outp,
                                               float* __restrict__ attn) {
  extern __shared__ bf16 smem[];
  const int h = (int)blockIdx.x;
  const int tid = (int)threadIdx.x;

  if (h >= 256) {  // ---- norm role ----
    const int nb = h - 256;
    size_t base = (size_t)nb * 4096 + tid;
#pragma unroll
    for (int it = 0; it < 8; ++it) {
      size_t ch = base + (size_t)it * 512;
      int row = (int)(ch >> 8);  // 256 chunks per 2048-elem row
      float ri = rinv[row];
      bf16x8 v = reinterpret_cast<const bf16x8*>(wbf)[ch];
      float4 lo, hi;
      lo.x = (float)v[0] * ri; lo.y = (float)v[1] * ri;
      lo.z = (float)v[2] * ri; lo.w = (float)v[3] * ri;
      hi.x = (float)v[4] * ri; hi.y = (float)v[5] * ri;
      hi.z = (float)v[6] * ri; hi.w = (float)v[7] * ri;
      reinterpret_cast<float4*>(attn)[ch * 2] = lo;
      reinterpret_cast<float4*>(attn)[ch * 2 + 1] = hi;
    }
    return;
  }

  // ---- pv GEMM role (round-10 verbatim) ----
  const int bb = h & 7, pos = h >> 3;
  const int mtile = pos >> 2, ntile = pos & 3;
  const int lane = tid & 63, wid = tid >> 6;
  const int wm = wid >> 2, wn = wid & 3;
  const int cc = lane & 15, g = lane >> 4;
  const bf16* Ab = wbf + (size_t)bb * SEQ * SEQ + (size_t)(mtile * 256) * SEQ;
  const bf16* Bb = vt + (size_t)bb * EMBED * SEQ + (size_t)(ntile * 256) * SEQ;
  f32x4 acc[8][4];
#pragma unroll
  for (int i = 0; i < 8; ++i)
#pragma unroll
    for (int j = 0; j < 4; ++j) acc[i][j] = (f32x4){0.f, 0.f, 0.f, 0.f};
  gemm_core<SEQ, SEQ, SEQ>(Ab, Bb, smem, acc);

  const int c0 = ntile * 256 + wn * 64;
#pragma unroll
  for (int mi = 0; mi < 8; ++mi) {
#pragma unroll
    for (int j = 0; j < 4; ++j) {
      size_t grow = (size_t)bb * SEQ + mtile * 256 + wm * 128 + mi * 16 + g * 4 + j;
      float ri = rinv[grow];
      size_t base = grow * EMBED;
#pragma unroll
      for (int ni = 0; ni < 4; ++ni) {
        size_t off = base + c0 + ni * 16 + cc;
        outp[off] = xin[off] + acc[mi][ni][j] * ri;
      }
    }
  }
}

extern "C" void kernel_launch(void* const* d_in, const int* in_sizes, int n_in,
                              void* d_out, int out_size, void* d_ws, size_t ws_size,
                              hipStream_t stream) {
  const float* x = (const float*)d_in[0];
  const float* Wq = (const float*)d_in[1];
  const float* bq = (const float*)d_in[2];
  const float* Wk = (const float*)d_in[3];
  const float* bk = (const float*)d_in[4];
  const float* Wv = (const float*)d_in[5];
  const float* bv = (const float*)d_in[6];
  const float* gamma = (const float*)d_in[7];
  const float* beta = (const float*)d_in[8];

  float* out = (float*)d_out;
  float* attn = out + (size_t)BATCH * SEQ * EMBED;

  bf16* qbuf = (bf16*)d_out;  // Q,K live in the output region until PV
  bf16* kbuf = qbuf + (size_t)BATCH * SEQ * EMBED;

  // ws: [0,32M) xn | [32M,38M) W bf16 | later [0,64M) wbf | [64M,96M) Vt
  //     [96M,96.5M) partial (16384x8 f32) | [96.5M,+64K) rinv
  bf16* xn = (bf16*)d_ws;
  bf16* wall = xn + (size_t)BATCH * SEQ * EMBED;
  bf16* wbf = (bf16*)d_ws;
  bf16* vt = (bf16*)d_ws + (size_t)BATCH * SEQ * SEQ;
  float* partial = (float*)((char*)d_ws + 100663296ull);
  float* rinv = (float*)((char*)d_ws + 100663296ull + 524288ull);

  hipFuncSetAttribute((const void*)k_qkv256, hipFuncAttributeMaxDynamicSharedMemorySize, 131072);
  hipFuncSetAttribute((const void*)k_scores256, hipFuncAttributeMaxDynamicSharedMemorySize, 131072);
  hipFuncSetAttribute((const void*)k_pv256, hipFuncAttributeMaxDynamicSharedMemorySize, 131072);

  k_pre<<<BATCH * SEQ + 3072, 256, 0, stream>>>(x, gamma, beta, Wq, Wk, Wv, xn, wall);
  k_qkv256<<<768, 512, 131072, stream>>>(xn, wall, bq, bk, bv, qbuf, kbuf, vt);
  k_scores256<<<512, 512, 131072, stream>>>(qbuf, kbuf, wbf, partial);
  k_rowsum<<<64, 256, 0, stream>>>(partial, rinv);
  k_pv256<<<1280, 512, 131072, stream>>>(wbf, vt, rinv, x, out, attn);
}